// Round 13
// baseline (470.099 us; speedup 1.0000x reference)
//
#include <hip/hip_runtime.h>
#include <hip/hip_bf16.h>

// 3-layer GCN. R13: (1) agg128/agg40 gathers widened to uint2 (8B/lane) —
// 2 (resp. 4) edges in flight per load instruction, half the issue count per
// byte; shuffle-combine parity halves at the end. (2) prepw folded into
// bucket_count2 (-1 dispatch). Falsifier: if agg128 time doesn't move with
// FETCH unchanged, it's purely L3-random-BW-bound (roofline).

#define D_H 128
#define SCAN_CHUNK 1024

typedef unsigned int uint32;
typedef unsigned short ushort16;
typedef __attribute__((ext_vector_type(8))) short short8v;   // 8 bf16 = 4 VGPR
typedef __attribute__((ext_vector_type(4))) float float4v;   // MFMA acc

__device__ __forceinline__ ushort16 f2bf(float f) {
    union { float f; uint32 u; } v;
    v.f = f;
    uint32 u = v.u;
    return (ushort16)((u + 0x7fffu + ((u >> 16) & 1u)) >> 16);  // RNE
}
__device__ __forceinline__ float2 bf2f2(uint32 u) {
    union { uint32 i; float f; } a, b;
    a.i = u << 16;
    b.i = u & 0xffff0000u;
    return make_float2(a.f, b.f);
}

// --- fused: weight transpose/cast (gid<24576) + bucket counting -------------
__global__ __launch_bounds__(256) void bucket_count2_kernel(
    const int* __restrict__ src, const int* __restrict__ dst,
    int* __restrict__ M, int* __restrict__ M2, int E, int nbuck,
    const float* __restrict__ W0, const float* __restrict__ W1,
    const float* __restrict__ W2, ushort16* __restrict__ Wt0,
    ushort16* __restrict__ Wt1, ushort16* __restrict__ Wt2) {
    int gid = blockIdx.x * 256 + threadIdx.x;  // 128*256 = 32768
    if (gid < 16384) {
        int n = gid & 127, k = gid >> 7;
        Wt0[n * 128 + k] = f2bf(W0[k * 128 + n]);
        Wt1[n * 128 + k] = f2bf(W1[k * 128 + n]);
    } else if (gid < 24576) {
        int i2 = gid - 16384;
        int n = i2 >> 7, k = i2 & 127;
        Wt2[n * 128 + k] = (n < 40) ? f2bf(W2[k * 40 + n]) : (ushort16)0;
    }
    __shared__ int h[512], h2[512];
    for (int i = threadIdx.x; i < nbuck; i += 256) { h[i] = 0; h2[i] = 0; }
    __syncthreads();
    int j = blockIdx.x;  // 128 blocks
    int epb = (E + 127) >> 7;
    int estart = j * epb, eend = min(estart + epb, E);
    for (int e = estart + threadIdx.x; e < eend; e += 256) {
        atomicAdd(&h[dst[e] >> 8], 1);
        atomicAdd(&h2[src[e] >> 8], 1);
    }
    __syncthreads();
    for (int b = threadIdx.x; b < nbuck; b += 256) {
        M[(size_t)b * 128 + j] = h[b];
        M2[(size_t)b * 128 + j] = h2[b];
    }
}

// ------- fused scans: blocks [0,g) handle M, [g,2g) handle M2 ---------------
__global__ __launch_bounds__(256) void scan1f_kernel(
    const int* __restrict__ M, const int* __restrict__ M2,
    int* __restrict__ bsum, int g, int n) {
    int half = (blockIdx.x >= g) ? 1 : 0;
    int blk = blockIdx.x - half * g;
    const int* deg = half ? M2 : M;
    int tid = threadIdx.x;
    int base = blk * SCAN_CHUNK + tid * 4;
    int4 v = make_int4(0, 0, 0, 0);
    if (base + 3 < n) {
        v = *(const int4*)(deg + base);
    } else {
        if (base + 0 < n) v.x = deg[base + 0];
        if (base + 1 < n) v.y = deg[base + 1];
        if (base + 2 < n) v.z = deg[base + 2];
        if (base + 3 < n) v.w = deg[base + 3];
    }
    int s = v.x + v.y + v.z + v.w;
    __shared__ int red[256];
    red[tid] = s;
    __syncthreads();
#pragma unroll
    for (int off = 128; off > 0; off >>= 1) {
        if (tid < off) red[tid] += red[tid + off];
        __syncthreads();
    }
    if (tid == 0) bsum[blockIdx.x] = red[0];
}

__global__ __launch_bounds__(256) void scan3f_kernel(
    const int* __restrict__ M, const int* __restrict__ M2,
    const int* __restrict__ bsum, int* __restrict__ Mx, int* __restrict__ Mx2,
    int g, int n) {
    int half = (blockIdx.x >= g) ? 1 : 0;
    int blk = blockIdx.x - half * g;
    const int* deg = half ? M2 : M;
    int* outp = half ? Mx2 : Mx;
    int tid = threadIdx.x;
    int base = blk * SCAN_CHUNK + tid * 4;
    int4 v = make_int4(0, 0, 0, 0);
    if (base + 3 < n) {
        v = *(const int4*)(deg + base);
    } else {
        if (base + 0 < n) v.x = deg[base + 0];
        if (base + 1 < n) v.y = deg[base + 1];
        if (base + 2 < n) v.z = deg[base + 2];
        if (base + 3 < n) v.w = deg[base + 3];
    }
    int s = v.x + v.y + v.z + v.w;

    __shared__ int bs[128];
    if (tid < 128) bs[tid] = (tid < g) ? bsum[half * g + tid] : 0;
    __syncthreads();
#pragma unroll
    for (int off = 1; off < 128; off <<= 1) {
        int t = (tid < 128 && tid >= off) ? bs[tid - off] : 0;
        __syncthreads();
        if (tid < 128) bs[tid] += t;
        __syncthreads();
    }
    int blockbase = (blk == 0) ? 0 : bs[blk - 1];
    int total = bs[g - 1];

    __shared__ int sc[256];
    sc[tid] = s;
    __syncthreads();
#pragma unroll
    for (int off = 1; off < 256; off <<= 1) {
        int t = (tid >= off) ? sc[tid - off] : 0;
        __syncthreads();
        sc[tid] += t;
        __syncthreads();
    }
    int excl = sc[tid] - s + blockbase;
    int p0 = excl;
    int p1 = p0 + v.x;
    int p2 = p1 + v.y;
    int p3 = p2 + v.z;
    if (base + 3 < n) {
        *(int4*)(outp + base) = make_int4(p0, p1, p2, p3);
    } else {
        if (base + 0 < n) outp[base + 0] = p0;
        if (base + 1 < n) outp[base + 1] = p1;
        if (base + 2 < n) outp[base + 2] = p2;
    }
    if (blk == g - 1 && tid == 0) outp[n] = total;
}

// ------- fused bucket scatter: dst-packed + src-raw, one edge pass ----------
__global__ __launch_bounds__(256) void bucket_scatter2_kernel(
    const int* __restrict__ src, const int* __restrict__ dst,
    const int* __restrict__ Mx, const int* __restrict__ Mx2,
    uint32* __restrict__ packed, uint32* __restrict__ sp, int E, int nbuck) {
    __shared__ int cb1[512], c1[512], cb2[512], c2[512];
    int j = blockIdx.x;
    for (int i = threadIdx.x; i < nbuck; i += 256) {
        cb1[i] = Mx[(size_t)i * 128 + j];
        c1[i] = 0;
        cb2[i] = Mx2[(size_t)i * 128 + j];
        c2[i] = 0;
    }
    __syncthreads();
    int epb = (E + 127) >> 7;
    int estart = j * epb, eend = min(estart + epb, E);
    for (int e = estart + threadIdx.x; e < eend; e += 256) {
        int s = src[e], d = dst[e];
        int b = d >> 8;
        int r = atomicAdd(&c1[b], 1);
        packed[cb1[b] + r] = ((uint32)s << 8) | (uint32)(d & 255);
        int b2 = s >> 8;
        int r2 = atomicAdd(&c2[b2], 1);
        sp[cb2[b2] + r2] = (uint32)s;
    }
}

// ---- fused per-bucket CSR finalize (row_ptr/nd/ssrc) + src count (ns) ------
__global__ __launch_bounds__(256) void csr_src_kernel(
    const uint32* __restrict__ packed, const int* __restrict__ Mx,
    const uint32* __restrict__ sp, const int* __restrict__ Mx2,
    int* __restrict__ row_ptr, float* __restrict__ nd, float* __restrict__ ns,
    int* __restrict__ ssrc, int E, int N, int nbuck) {
    __shared__ int cnt[256], pos0[256], cur[256], sc[256], cnt2[256];
    int b = blockIdx.x, tid = threadIdx.x;
    int lo = Mx[(size_t)b * 128];
    int hi = (b == nbuck - 1) ? E : Mx[(size_t)(b + 1) * 128];
    int lo2 = Mx2[(size_t)b * 128];
    int hi2 = (b == nbuck - 1) ? E : Mx2[(size_t)(b + 1) * 128];
    cnt[tid] = 0;
    cur[tid] = 0;
    cnt2[tid] = 0;
    __syncthreads();
    for (int e = lo + tid; e < hi; e += 256)
        atomicAdd(&cnt[packed[e] & 255u], 1);
    for (int e = lo2 + tid; e < hi2; e += 256)
        atomicAdd(&cnt2[sp[e] & 255u], 1);
    __syncthreads();
    int c = cnt[tid];
    sc[tid] = c;
    __syncthreads();
#pragma unroll
    for (int off = 1; off < 256; off <<= 1) {
        int t = (tid >= off) ? sc[tid - off] : 0;
        __syncthreads();
        sc[tid] += t;
        __syncthreads();
    }
    int excl = sc[tid] - c;
    pos0[tid] = lo + excl;
    int node = b * 256 + tid;
    if (node < N) {
        row_ptr[node] = lo + excl;
        nd[node] = rsqrtf((float)max(c, 1));
        ns[node] = rsqrtf((float)max(cnt2[tid], 1));
    }
    if (b == 0 && tid == 0) row_ptr[N] = E;
    __syncthreads();
    for (int e = lo + tid; e < hi; e += 256) {
        uint32 p = packed[e];
        int local = (int)(p & 255u);
        int r = atomicAdd(&cur[local], 1);
        ssrc[pos0[local] + r] = (int)(p >> 8);
    }
}

// ---------------- MFMA GEMM (layers 0/1): 128x128 out, bf16 -----------------
template <bool XBF16, bool FUSE_BN>
__global__ __launch_bounds__(256) void gemm_mfma_kernel(
    const void* __restrict__ Xv, const ushort16* __restrict__ Wt,
    const float* __restrict__ ns, const float* __restrict__ stats,
    const float* __restrict__ gamma, const float* __restrict__ beta,
    float invn, ushort16* __restrict__ Yb, int nrows) {
    constexpr int LDK = 72;
    __shared__ short As[128 * LDK];
    __shared__ short Ws[128 * LDK];
    __shared__ float abl[256];
    int tid = threadIdx.x;
    int row0 = blockIdx.x * 128;
    int wave = tid >> 6, lane = tid & 63;
    int wm = (wave >> 1) * 64, wn = (wave & 1) * 64;
    int l15 = lane & 15, quad = lane >> 4;
    float4v acc[4][4] = {{}};

    if (FUSE_BN) {
        if (tid < 128) {
            float mean = stats[tid] * invn;
            float var = stats[128 + tid] * invn - mean * mean;
            float a = rsqrtf(var + 1e-5f) * gamma[tid];
            abl[tid] = a;
            abl[128 + tid] = beta[tid] - mean * a;
        }
        __syncthreads();
    }

#pragma unroll
    for (int p = 0; p < 2; ++p) {
        int k0 = p * 64;
        {
            int srow = tid >> 1;
            int half = (tid & 1) * 32;
            int grow = row0 + srow;
            bool ok = grow < nrows;
            float sc = ok ? ns[grow] : 0.f;
            uint32 outu[16];
            if (XBF16) {
                const uint4* xp = (const uint4*)((const uint32*)Xv +
                                                 (size_t)grow * 64 + ((k0 + half) >> 1));
                uint4 u4[4];
#pragma unroll
                for (int q = 0; q < 4; ++q)
                    u4[q] = ok ? xp[q] : make_uint4(0, 0, 0, 0);
                const uint32* uu = (const uint32*)u4;
#pragma unroll
                for (int j = 0; j < 16; ++j) {
                    float2 f = bf2f2(uu[j]);
                    if (FUSE_BN) {
                        int c = k0 + half + j * 2;
                        f.x = fmaxf(fmaf(f.x, abl[c], abl[128 + c]), 0.f);
                        f.y = fmaxf(fmaf(f.y, abl[c + 1], abl[128 + c + 1]), 0.f);
                    }
                    outu[j] = (uint32)f2bf(f.x * sc) | ((uint32)f2bf(f.y * sc) << 16);
                }
            } else {
                const float4* xp = (const float4*)((const float*)Xv +
                                                   (size_t)grow * 128 + k0 + half);
                float4 f4[8];
#pragma unroll
                for (int q = 0; q < 8; ++q)
                    f4[q] = ok ? xp[q] : make_float4(0.f, 0.f, 0.f, 0.f);
                const float* ff = (const float*)f4;
#pragma unroll
                for (int j = 0; j < 16; ++j) {
                    float fx = ff[2 * j], fy = ff[2 * j + 1];
                    outu[j] = (uint32)f2bf(fx * sc) | ((uint32)f2bf(fy * sc) << 16);
                }
            }
            uint4* dstA = (uint4*)&As[srow * LDK + half];
#pragma unroll
            for (int q = 0; q < 4; ++q) dstA[q] = ((uint4*)outu)[q];
            const uint4* wp = (const uint4*)((const uint32*)Wt +
                                             srow * 64 + ((k0 + half) >> 1));
            uint4* dstW = (uint4*)&Ws[srow * LDK + half];
#pragma unroll
            for (int q = 0; q < 4; ++q) dstW[q] = wp[q];
        }
        __syncthreads();
#pragma unroll
        for (int ks = 0; ks < 2; ++ks) {
            int koff = ks * 32 + quad * 8;
            short8v a[4], b[4];
#pragma unroll
            for (int t = 0; t < 4; ++t)
                a[t] = *(const short8v*)&As[(wm + t * 16 + l15) * LDK + koff];
#pragma unroll
            for (int u = 0; u < 4; ++u)
                b[u] = *(const short8v*)&Ws[(wn + u * 16 + l15) * LDK + koff];
#pragma unroll
            for (int t = 0; t < 4; ++t)
#pragma unroll
                for (int u = 0; u < 4; ++u)
                    acc[t][u] = __builtin_amdgcn_mfma_f32_16x16x32_bf16(
                        a[t], b[u], acc[t][u], 0, 0, 0);
        }
        __syncthreads();
    }
#pragma unroll
    for (int t = 0; t < 4; ++t) {
#pragma unroll
        for (int r = 0; r < 4; ++r) {
            int grow = row0 + wm + t * 16 + quad * 4 + r;
            if (grow < nrows) {
#pragma unroll
                for (int u = 0; u < 4; ++u)
                    Yb[(size_t)grow * 128 + wn + u * 16 + l15] = f2bf(acc[t][u][r]);
            }
        }
    }
}

// ---- layer-2 projection: Y2b = bf16((ns*relu(bn1(Ab))) @ W2), 128->64 ------
__global__ __launch_bounds__(256) void gemm_mfma2_kernel(
    const uint32* __restrict__ Xb, const ushort16* __restrict__ Wt2,
    const float* __restrict__ ns, const float* __restrict__ stats,
    const float* __restrict__ gamma, const float* __restrict__ beta,
    float invn, ushort16* __restrict__ Y2b, int nrows) {
    constexpr int LDK = 72;
    __shared__ short As[128 * LDK];
    __shared__ short Ws[64 * LDK];
    __shared__ float abl[256];
    int tid = threadIdx.x;
    int row0 = blockIdx.x * 128;
    int wave = tid >> 6, lane = tid & 63;
    int wm = (wave >> 1) * 64, wn = (wave & 1) * 32;
    int l15 = lane & 15, quad = lane >> 4;
    float4v acc[4][2] = {{}};

    if (tid < 128) {
        float mean = stats[tid] * invn;
        float var = stats[128 + tid] * invn - mean * mean;
        float a = rsqrtf(var + 1e-5f) * gamma[tid];
        abl[tid] = a;
        abl[128 + tid] = beta[tid] - mean * a;
    }
    __syncthreads();

#pragma unroll
    for (int p = 0; p < 2; ++p) {
        int k0 = p * 64;
        {
            int srow = tid >> 1;
            int half = (tid & 1) * 32;
            int grow = row0 + srow;
            bool ok = grow < nrows;
            float sc = ok ? ns[grow] : 0.f;
            const uint4* xp = (const uint4*)(Xb + (size_t)grow * 64 + ((k0 + half) >> 1));
            uint4 u4[4];
#pragma unroll
            for (int q = 0; q < 4; ++q)
                u4[q] = ok ? xp[q] : make_uint4(0, 0, 0, 0);
            const uint32* uu = (const uint32*)u4;
            uint32 outu[16];
#pragma unroll
            for (int j = 0; j < 16; ++j) {
                float2 f = bf2f2(uu[j]);
                int c = k0 + half + j * 2;
                f.x = fmaxf(fmaf(f.x, abl[c], abl[128 + c]), 0.f);
                f.y = fmaxf(fmaf(f.y, abl[c + 1], abl[128 + c + 1]), 0.f);
                outu[j] = (uint32)f2bf(f.x * sc) | ((uint32)f2bf(f.y * sc) << 16);
            }
            uint4* dstA = (uint4*)&As[srow * LDK + half];
#pragma unroll
            for (int q = 0; q < 4; ++q) dstA[q] = ((uint4*)outu)[q];
        }
        {
            int srow = tid >> 2;           // 64 rows
            int off = (tid & 3) * 16;      // 16 shorts each
            const uint4* wp = (const uint4*)((const uint32*)Wt2 +
                                             srow * 64 + ((k0 + off) >> 1));
            uint4* dw = (uint4*)&Ws[srow * LDK + off];
            dw[0] = wp[0];
            dw[1] = wp[1];
        }
        __syncthreads();
#pragma unroll
        for (int ks = 0; ks < 2; ++ks) {
            int koff = ks * 32 + quad * 8;
            short8v a[4], b[2];
#pragma unroll
            for (int t = 0; t < 4; ++t)
                a[t] = *(const short8v*)&As[(wm + t * 16 + l15) * LDK + koff];
#pragma unroll
            for (int u = 0; u < 2; ++u)
                b[u] = *(const short8v*)&Ws[(wn + u * 16 + l15) * LDK + koff];
#pragma unroll
            for (int t = 0; t < 4; ++t)
#pragma unroll
                for (int u = 0; u < 2; ++u)
                    acc[t][u] = __builtin_amdgcn_mfma_f32_16x16x32_bf16(
                        a[t], b[u], acc[t][u], 0, 0, 0);
        }
        __syncthreads();
    }
#pragma unroll
    for (int t = 0; t < 4; ++t) {
#pragma unroll
        for (int r = 0; r < 4; ++r) {
            int grow = row0 + wm + t * 16 + quad * 4 + r;
            if (grow < nrows) {
#pragma unroll
                for (int u = 0; u < 2; ++u)
                    Y2b[(size_t)grow * 64 + wn + u * 16 + l15] = f2bf(acc[t][u][r]);
            }
        }
    }
}

// --- CSR aggregation (bf16 in/out), uint2 gathers, 2 edges/instruction ------
// lane: par=lane>>5 (edge parity), l32=lane&31 (4 cols via uint2).
__global__ __launch_bounds__(256) void agg128_kernel(
    const uint32* __restrict__ xwb, const int* __restrict__ row_ptr,
    const int* __restrict__ ssrc, const float* __restrict__ nd,
    uint32* __restrict__ outb, int n) {
    int node = blockIdx.x * 4 + (threadIdx.x >> 6);
    if (node >= n) return;
    int lane = threadIdx.x & 63;
    int par = lane >> 5, l32 = lane & 31;
    int beg = row_ptr[node], end = row_ptr[node + 1];
    float x0 = 0.f, x1 = 0.f, x2 = 0.f, x3 = 0.f;
    int e = beg;
    for (; e + 8 <= end; e += 8) {
        int s[4];
#pragma unroll
        for (int j = 0; j < 4; ++j) s[j] = ssrc[e + 2 * j + par];
        uint2 u[4];
#pragma unroll
        for (int j = 0; j < 4; ++j)
            u[j] = *(const uint2*)(xwb + (size_t)s[j] * 64 + l32 * 2);
#pragma unroll
        for (int j = 0; j < 4; ++j) {
            float2 a = bf2f2(u[j].x), b = bf2f2(u[j].y);
            x0 += a.x; x1 += a.y; x2 += b.x; x3 += b.y;
        }
    }
    for (; e + 2 <= end; e += 2) {
        uint2 u = *(const uint2*)(xwb + (size_t)ssrc[e + par] * 64 + l32 * 2);
        float2 a = bf2f2(u.x), b = bf2f2(u.y);
        x0 += a.x; x1 += a.y; x2 += b.x; x3 += b.y;
    }
    if (e < end && par == 0) {
        uint2 u = *(const uint2*)(xwb + (size_t)ssrc[e] * 64 + l32 * 2);
        float2 a = bf2f2(u.x), b = bf2f2(u.y);
        x0 += a.x; x1 += a.y; x2 += b.x; x3 += b.y;
    }
    x0 += __shfl_down(x0, 32, 64);
    x1 += __shfl_down(x1, 32, 64);
    x2 += __shfl_down(x2, 32, 64);
    x3 += __shfl_down(x3, 32, 64);
    if (par == 0) {
        float s = nd[node];
        uint2 o;
        o.x = (uint32)f2bf(x0 * s) | ((uint32)f2bf(x1 * s) << 16);
        o.y = (uint32)f2bf(x2 * s) | ((uint32)f2bf(x3 * s) << 16);
        *(uint2*)(outb + (size_t)node * 64 + l32 * 2) = o;
    }
}

// ---- layer-2 aggregation: uint2 gathers, 4 edges/instruction ----------------
// lane: quad=lane>>4 (edge slot 0..3), l16=lane&15 (4 cols of 64 via uint2).
__global__ __launch_bounds__(256) void agg40_kernel(
    const uint32* __restrict__ y2b, const int* __restrict__ row_ptr,
    const int* __restrict__ ssrc, const float* __restrict__ nd,
    const float* __restrict__ bias, float* __restrict__ out, int n) {
    int node = blockIdx.x * 4 + (threadIdx.x >> 6);
    if (node >= n) return;
    int lane = threadIdx.x & 63;
    int quad = lane >> 4, l16 = lane & 15;
    int beg = row_ptr[node], end = row_ptr[node + 1];
    float x0 = 0.f, x1 = 0.f, x2 = 0.f, x3 = 0.f;
    int e = beg;
    for (; e + 8 <= end; e += 8) {
        int s0 = ssrc[e + quad];
        int s1 = ssrc[e + 4 + quad];
        uint2 u0 = *(const uint2*)(y2b + (size_t)s0 * 32 + l16 * 2);
        uint2 u1 = *(const uint2*)(y2b + (size_t)s1 * 32 + l16 * 2);
        float2 a0 = bf2f2(u0.x), b0 = bf2f2(u0.y);
        float2 a1 = bf2f2(u1.x), b1 = bf2f2(u1.y);
        x0 += a0.x + a1.x; x1 += a0.y + a1.y;
        x2 += b0.x + b1.x; x3 += b0.y + b1.y;
    }
    int r = end - e;
    if (quad < r) {
        uint2 u = *(const uint2*)(y2b + (size_t)ssrc[e + quad] * 32 + l16 * 2);
        float2 a = bf2f2(u.x), b = bf2f2(u.y);
        x0 += a.x; x1 += a.y; x2 += b.x; x3 += b.y;
    }
    if (quad + 4 < r) {
        uint2 u = *(const uint2*)(y2b + (size_t)ssrc[e + 4 + quad] * 32 + l16 * 2);
        float2 a = bf2f2(u.x), b = bf2f2(u.y);
        x0 += a.x; x1 += a.y; x2 += b.x; x3 += b.y;
    }
    x0 += __shfl_down(x0, 32, 64);
    x1 += __shfl_down(x1, 32, 64);
    x2 += __shfl_down(x2, 32, 64);
    x3 += __shfl_down(x3, 32, 64);
    x0 += __shfl_down(x0, 16, 64);
    x1 += __shfl_down(x1, 16, 64);
    x2 += __shfl_down(x2, 16, 64);
    x3 += __shfl_down(x3, 16, 64);
    if (lane < 10) {  // cols 0..39 = lanes 0..9 x 4 cols
        float s = nd[node];
        int c = lane * 4;
        float4 bb = *(const float4*)&bias[c];
        float4 o;
        o.x = fmaf(x0, s, bb.x);
        o.y = fmaf(x1, s, bb.y);
        o.z = fmaf(x2, s, bb.z);
        o.w = fmaf(x3, s, bb.w);
        *(float4*)(out + (size_t)node * 40 + c) = o;
    }
}

// -------- batchnorm stats (bf16 input, uint4 loads, 8 cols/thread) ----------
__global__ __launch_bounds__(256) void bn_reduce_kernel(const uint4* __restrict__ x4,
                                                        float* __restrict__ stats, int n) {
    int tid = threadIdx.x;
    int ctile = tid & 15;    // 16 col-tiles of 8 cols
    int rgrp = tid >> 4;     // 16 row groups
    float s[8] = {}, s2[8] = {};
    for (int r = blockIdx.x * 16 + rgrp; r < n; r += gridDim.x * 16) {
        uint4 u = x4[(size_t)r * 16 + ctile];
        uint32 uu[4] = {u.x, u.y, u.z, u.w};
#pragma unroll
        for (int q = 0; q < 4; ++q) {
            float2 v = bf2f2(uu[q]);
            s[q * 2] += v.x;
            s[q * 2 + 1] += v.y;
            s2[q * 2] = fmaf(v.x, v.x, s2[q * 2]);
            s2[q * 2 + 1] = fmaf(v.y, v.y, s2[q * 2 + 1]);
        }
    }
    __shared__ float ls[128], ls2[128];
    if (tid < 128) { ls[tid] = 0.f; ls2[tid] = 0.f; }
    __syncthreads();
#pragma unroll
    for (int j = 0; j < 8; ++j) {
        atomicAdd(&ls[ctile * 8 + j], s[j]);
        atomicAdd(&ls2[ctile * 8 + j], s2[j]);
    }
    __syncthreads();
    if (tid < 128) {
        atomicAdd(&stats[tid], ls[tid]);
        atomicAdd(&stats[128 + tid], ls2[tid]);
    }
}

// ---------------- launch ----------------

extern "C" void kernel_launch(void* const* d_in, const int* in_sizes, int n_in,
                              void* d_out, int out_size, void* d_ws, size_t ws_size,
                              hipStream_t stream) {
    const float* feat = (const float*)d_in[0];
    const int* edge_src = (const int*)d_in[1];
    const int* edge_dst = (const int*)d_in[2];
    const float* W0 = (const float*)d_in[3];
    const float* W1 = (const float*)d_in[4];
    const float* W2 = (const float*)d_in[5];
    const float* b2 = (const float*)d_in[6];
    const float* g0 = (const float*)d_in[7];
    const float* beta0 = (const float*)d_in[8];
    const float* g1 = (const float*)d_in[9];
    const float* beta1 = (const float*)d_in[10];
    float* out = (float*)d_out;

    const int N = in_sizes[0] / D_H;   // 100000
    const int E = in_sizes[1];         // 1600000
    const int nbuck = (N + 255) >> 8;  // 391
    const float invN = 1.0f / (float)N;

    char* p = (char*)d_ws;
    auto alloc = [&](size_t bytes) {
        char* r = p;
        p += (bytes + 255) & ~(size_t)255;
        return r;
    };
    uint32* Ab = (uint32*)alloc((size_t)N * D_H * 2);   // bf16 A (packed pairs)
    uint32* Bb = (uint32*)alloc((size_t)N * D_H * 2);   // bf16 B / Y2b
    float* ns = (float*)alloc((size_t)N * 4);
    float* nd = (float*)alloc((size_t)N * 4);
    int* row_ptr = (int*)alloc((size_t)(N + 1) * 4);
    int* ssrc = (int*)alloc((size_t)E * 4);
    uint32* packed = (uint32*)alloc((size_t)E * 4);
    uint32* sp = (uint32*)alloc((size_t)E * 4);
    int* M = (int*)alloc((size_t)nbuck * 128 * 4);
    int* Mx = (int*)alloc(((size_t)nbuck * 128 + 4) * 4);
    int* M2 = (int*)alloc((size_t)nbuck * 128 * 4);
    int* Mx2 = (int*)alloc(((size_t)nbuck * 128 + 4) * 4);
    int* bsum = (int*)alloc(256 * 4);
    float* stats0 = (float*)alloc(256 * 4);   // contiguous with stats1
    float* stats1 = (float*)alloc(256 * 4);
    ushort16* Wt0 = (ushort16*)alloc(128 * 128 * 2);
    ushort16* Wt1 = (ushort16*)alloc(128 * 128 * 2);
    ushort16* Wt2 = (ushort16*)alloc(64 * 128 * 2);
    (void)ws_size;

    hipMemsetAsync(stats0, 0, 2048, stream);  // stats0 + stats1 (adjacent)

    const int ggrid = (N + 127) / 128;
    const int agrid = (N + 3) / 4;
    const int nM = nbuck * 128;                            // 50048
    const int sgridM = (nM + SCAN_CHUNK - 1) / SCAN_CHUNK; // 49

    bucket_count2_kernel<<<128, 256, 0, stream>>>(edge_src, edge_dst, M, M2, E, nbuck,
                                                  W0, W1, W2, Wt0, Wt1, Wt2);
    scan1f_kernel<<<2 * sgridM, 256, 0, stream>>>(M, M2, bsum, sgridM, nM);
    scan3f_kernel<<<2 * sgridM, 256, 0, stream>>>(M, M2, bsum, Mx, Mx2, sgridM, nM);
    bucket_scatter2_kernel<<<128, 256, 0, stream>>>(edge_src, edge_dst, Mx, Mx2,
                                                    packed, sp, E, nbuck);
    csr_src_kernel<<<nbuck, 256, 0, stream>>>(packed, Mx, sp, Mx2, row_ptr, nd, ns,
                                              ssrc, E, N, nbuck);

    // layer 0
    gemm_mfma_kernel<false, false><<<ggrid, 256, 0, stream>>>(
        feat, Wt0, ns, nullptr, nullptr, nullptr, invN, (ushort16*)Bb, N);
    agg128_kernel<<<agrid, 256, 0, stream>>>(Bb, row_ptr, ssrc, nd, Ab, N);
    bn_reduce_kernel<<<512, 256, 0, stream>>>((const uint4*)Ab, stats0, N);

    // layer 1
    gemm_mfma_kernel<true, true><<<ggrid, 256, 0, stream>>>(
        Ab, Wt1, ns, stats0, g0, beta0, invN, (ushort16*)Bb, N);
    agg128_kernel<<<agrid, 256, 0, stream>>>(Bb, row_ptr, ssrc, nd, Ab, N);
    bn_reduce_kernel<<<512, 256, 0, stream>>>((const uint4*)Ab, stats1, N);

    // layer 2: project (BN+relu+ns in staging) -> Y2b (N x 64 bf16); agg40 -> out
    gemm_mfma2_kernel<<<ggrid, 256, 0, stream>>>(
        Ab, Wt2, ns, stats1, g1, beta1, invN, (ushort16*)Bb, N);
    agg40_kernel<<<agrid, 256, 0, stream>>>(Bb, row_ptr, ssrc, nd, b2, out, N);
}

// Round 14
// 455.688 us; speedup vs baseline: 1.0316x; 1.0316x over previous
//
#include <hip/hip_runtime.h>
#include <hip/hip_bf16.h>

// 3-layer GCN. R14: agg128/agg40 main loops widened to 16-edge batches —
// 8 (resp. 4) uint2 gathers in flight per wave (R12's MLP depth at R13's
// halved instruction count). No register double-buffering (R10 lesson).
// R12=8 outstanding: 64us; R13=4: 65.5us -> MLP is the lever.

#define D_H 128
#define SCAN_CHUNK 1024

typedef unsigned int uint32;
typedef unsigned short ushort16;
typedef __attribute__((ext_vector_type(8))) short short8v;   // 8 bf16 = 4 VGPR
typedef __attribute__((ext_vector_type(4))) float float4v;   // MFMA acc

__device__ __forceinline__ ushort16 f2bf(float f) {
    union { float f; uint32 u; } v;
    v.f = f;
    uint32 u = v.u;
    return (ushort16)((u + 0x7fffu + ((u >> 16) & 1u)) >> 16);  // RNE
}
__device__ __forceinline__ float2 bf2f2(uint32 u) {
    union { uint32 i; float f; } a, b;
    a.i = u << 16;
    b.i = u & 0xffff0000u;
    return make_float2(a.f, b.f);
}

// --- fused: weight transpose/cast (gid<24576) + bucket counting -------------
__global__ __launch_bounds__(256) void bucket_count2_kernel(
    const int* __restrict__ src, const int* __restrict__ dst,
    int* __restrict__ M, int* __restrict__ M2, int E, int nbuck,
    const float* __restrict__ W0, const float* __restrict__ W1,
    const float* __restrict__ W2, ushort16* __restrict__ Wt0,
    ushort16* __restrict__ Wt1, ushort16* __restrict__ Wt2) {
    int gid = blockIdx.x * 256 + threadIdx.x;  // 128*256 = 32768
    if (gid < 16384) {
        int n = gid & 127, k = gid >> 7;
        Wt0[n * 128 + k] = f2bf(W0[k * 128 + n]);
        Wt1[n * 128 + k] = f2bf(W1[k * 128 + n]);
    } else if (gid < 24576) {
        int i2 = gid - 16384;
        int n = i2 >> 7, k = i2 & 127;
        Wt2[n * 128 + k] = (n < 40) ? f2bf(W2[k * 40 + n]) : (ushort16)0;
    }
    __shared__ int h[512], h2[512];
    for (int i = threadIdx.x; i < nbuck; i += 256) { h[i] = 0; h2[i] = 0; }
    __syncthreads();
    int j = blockIdx.x;  // 128 blocks
    int epb = (E + 127) >> 7;
    int estart = j * epb, eend = min(estart + epb, E);
    for (int e = estart + threadIdx.x; e < eend; e += 256) {
        atomicAdd(&h[dst[e] >> 8], 1);
        atomicAdd(&h2[src[e] >> 8], 1);
    }
    __syncthreads();
    for (int b = threadIdx.x; b < nbuck; b += 256) {
        M[(size_t)b * 128 + j] = h[b];
        M2[(size_t)b * 128 + j] = h2[b];
    }
}

// ------- fused scans: blocks [0,g) handle M, [g,2g) handle M2 ---------------
__global__ __launch_bounds__(256) void scan1f_kernel(
    const int* __restrict__ M, const int* __restrict__ M2,
    int* __restrict__ bsum, int g, int n) {
    int half = (blockIdx.x >= g) ? 1 : 0;
    int blk = blockIdx.x - half * g;
    const int* deg = half ? M2 : M;
    int tid = threadIdx.x;
    int base = blk * SCAN_CHUNK + tid * 4;
    int4 v = make_int4(0, 0, 0, 0);
    if (base + 3 < n) {
        v = *(const int4*)(deg + base);
    } else {
        if (base + 0 < n) v.x = deg[base + 0];
        if (base + 1 < n) v.y = deg[base + 1];
        if (base + 2 < n) v.z = deg[base + 2];
        if (base + 3 < n) v.w = deg[base + 3];
    }
    int s = v.x + v.y + v.z + v.w;
    __shared__ int red[256];
    red[tid] = s;
    __syncthreads();
#pragma unroll
    for (int off = 128; off > 0; off >>= 1) {
        if (tid < off) red[tid] += red[tid + off];
        __syncthreads();
    }
    if (tid == 0) bsum[blockIdx.x] = red[0];
}

__global__ __launch_bounds__(256) void scan3f_kernel(
    const int* __restrict__ M, const int* __restrict__ M2,
    const int* __restrict__ bsum, int* __restrict__ Mx, int* __restrict__ Mx2,
    int g, int n) {
    int half = (blockIdx.x >= g) ? 1 : 0;
    int blk = blockIdx.x - half * g;
    const int* deg = half ? M2 : M;
    int* outp = half ? Mx2 : Mx;
    int tid = threadIdx.x;
    int base = blk * SCAN_CHUNK + tid * 4;
    int4 v = make_int4(0, 0, 0, 0);
    if (base + 3 < n) {
        v = *(const int4*)(deg + base);
    } else {
        if (base + 0 < n) v.x = deg[base + 0];
        if (base + 1 < n) v.y = deg[base + 1];
        if (base + 2 < n) v.z = deg[base + 2];
        if (base + 3 < n) v.w = deg[base + 3];
    }
    int s = v.x + v.y + v.z + v.w;

    __shared__ int bs[128];
    if (tid < 128) bs[tid] = (tid < g) ? bsum[half * g + tid] : 0;
    __syncthreads();
#pragma unroll
    for (int off = 1; off < 128; off <<= 1) {
        int t = (tid < 128 && tid >= off) ? bs[tid - off] : 0;
        __syncthreads();
        if (tid < 128) bs[tid] += t;
        __syncthreads();
    }
    int blockbase = (blk == 0) ? 0 : bs[blk - 1];
    int total = bs[g - 1];

    __shared__ int sc[256];
    sc[tid] = s;
    __syncthreads();
#pragma unroll
    for (int off = 1; off < 256; off <<= 1) {
        int t = (tid >= off) ? sc[tid - off] : 0;
        __syncthreads();
        sc[tid] += t;
        __syncthreads();
    }
    int excl = sc[tid] - s + blockbase;
    int p0 = excl;
    int p1 = p0 + v.x;
    int p2 = p1 + v.y;
    int p3 = p2 + v.z;
    if (base + 3 < n) {
        *(int4*)(outp + base) = make_int4(p0, p1, p2, p3);
    } else {
        if (base + 0 < n) outp[base + 0] = p0;
        if (base + 1 < n) outp[base + 1] = p1;
        if (base + 2 < n) outp[base + 2] = p2;
    }
    if (blk == g - 1 && tid == 0) outp[n] = total;
}

// ------- fused bucket scatter: dst-packed + src-raw, one edge pass ----------
__global__ __launch_bounds__(256) void bucket_scatter2_kernel(
    const int* __restrict__ src, const int* __restrict__ dst,
    const int* __restrict__ Mx, const int* __restrict__ Mx2,
    uint32* __restrict__ packed, uint32* __restrict__ sp, int E, int nbuck) {
    __shared__ int cb1[512], c1[512], cb2[512], c2[512];
    int j = blockIdx.x;
    for (int i = threadIdx.x; i < nbuck; i += 256) {
        cb1[i] = Mx[(size_t)i * 128 + j];
        c1[i] = 0;
        cb2[i] = Mx2[(size_t)i * 128 + j];
        c2[i] = 0;
    }
    __syncthreads();
    int epb = (E + 127) >> 7;
    int estart = j * epb, eend = min(estart + epb, E);
    for (int e = estart + threadIdx.x; e < eend; e += 256) {
        int s = src[e], d = dst[e];
        int b = d >> 8;
        int r = atomicAdd(&c1[b], 1);
        packed[cb1[b] + r] = ((uint32)s << 8) | (uint32)(d & 255);
        int b2 = s >> 8;
        int r2 = atomicAdd(&c2[b2], 1);
        sp[cb2[b2] + r2] = (uint32)s;
    }
}

// ---- fused per-bucket CSR finalize (row_ptr/nd/ssrc) + src count (ns) ------
__global__ __launch_bounds__(256) void csr_src_kernel(
    const uint32* __restrict__ packed, const int* __restrict__ Mx,
    const uint32* __restrict__ sp, const int* __restrict__ Mx2,
    int* __restrict__ row_ptr, float* __restrict__ nd, float* __restrict__ ns,
    int* __restrict__ ssrc, int E, int N, int nbuck) {
    __shared__ int cnt[256], pos0[256], cur[256], sc[256], cnt2[256];
    int b = blockIdx.x, tid = threadIdx.x;
    int lo = Mx[(size_t)b * 128];
    int hi = (b == nbuck - 1) ? E : Mx[(size_t)(b + 1) * 128];
    int lo2 = Mx2[(size_t)b * 128];
    int hi2 = (b == nbuck - 1) ? E : Mx2[(size_t)(b + 1) * 128];
    cnt[tid] = 0;
    cur[tid] = 0;
    cnt2[tid] = 0;
    __syncthreads();
    for (int e = lo + tid; e < hi; e += 256)
        atomicAdd(&cnt[packed[e] & 255u], 1);
    for (int e = lo2 + tid; e < hi2; e += 256)
        atomicAdd(&cnt2[sp[e] & 255u], 1);
    __syncthreads();
    int c = cnt[tid];
    sc[tid] = c;
    __syncthreads();
#pragma unroll
    for (int off = 1; off < 256; off <<= 1) {
        int t = (tid >= off) ? sc[tid - off] : 0;
        __syncthreads();
        sc[tid] += t;
        __syncthreads();
    }
    int excl = sc[tid] - c;
    pos0[tid] = lo + excl;
    int node = b * 256 + tid;
    if (node < N) {
        row_ptr[node] = lo + excl;
        nd[node] = rsqrtf((float)max(c, 1));
        ns[node] = rsqrtf((float)max(cnt2[tid], 1));
    }
    if (b == 0 && tid == 0) row_ptr[N] = E;
    __syncthreads();
    for (int e = lo + tid; e < hi; e += 256) {
        uint32 p = packed[e];
        int local = (int)(p & 255u);
        int r = atomicAdd(&cur[local], 1);
        ssrc[pos0[local] + r] = (int)(p >> 8);
    }
}

// ---------------- MFMA GEMM (layers 0/1): 128x128 out, bf16 -----------------
template <bool XBF16, bool FUSE_BN>
__global__ __launch_bounds__(256) void gemm_mfma_kernel(
    const void* __restrict__ Xv, const ushort16* __restrict__ Wt,
    const float* __restrict__ ns, const float* __restrict__ stats,
    const float* __restrict__ gamma, const float* __restrict__ beta,
    float invn, ushort16* __restrict__ Yb, int nrows) {
    constexpr int LDK = 72;
    __shared__ short As[128 * LDK];
    __shared__ short Ws[128 * LDK];
    __shared__ float abl[256];
    int tid = threadIdx.x;
    int row0 = blockIdx.x * 128;
    int wave = tid >> 6, lane = tid & 63;
    int wm = (wave >> 1) * 64, wn = (wave & 1) * 64;
    int l15 = lane & 15, quad = lane >> 4;
    float4v acc[4][4] = {{}};

    if (FUSE_BN) {
        if (tid < 128) {
            float mean = stats[tid] * invn;
            float var = stats[128 + tid] * invn - mean * mean;
            float a = rsqrtf(var + 1e-5f) * gamma[tid];
            abl[tid] = a;
            abl[128 + tid] = beta[tid] - mean * a;
        }
        __syncthreads();
    }

#pragma unroll
    for (int p = 0; p < 2; ++p) {
        int k0 = p * 64;
        {
            int srow = tid >> 1;
            int half = (tid & 1) * 32;
            int grow = row0 + srow;
            bool ok = grow < nrows;
            float sc = ok ? ns[grow] : 0.f;
            uint32 outu[16];
            if (XBF16) {
                const uint4* xp = (const uint4*)((const uint32*)Xv +
                                                 (size_t)grow * 64 + ((k0 + half) >> 1));
                uint4 u4[4];
#pragma unroll
                for (int q = 0; q < 4; ++q)
                    u4[q] = ok ? xp[q] : make_uint4(0, 0, 0, 0);
                const uint32* uu = (const uint32*)u4;
#pragma unroll
                for (int j = 0; j < 16; ++j) {
                    float2 f = bf2f2(uu[j]);
                    if (FUSE_BN) {
                        int c = k0 + half + j * 2;
                        f.x = fmaxf(fmaf(f.x, abl[c], abl[128 + c]), 0.f);
                        f.y = fmaxf(fmaf(f.y, abl[c + 1], abl[128 + c + 1]), 0.f);
                    }
                    outu[j] = (uint32)f2bf(f.x * sc) | ((uint32)f2bf(f.y * sc) << 16);
                }
            } else {
                const float4* xp = (const float4*)((const float*)Xv +
                                                   (size_t)grow * 128 + k0 + half);
                float4 f4[8];
#pragma unroll
                for (int q = 0; q < 8; ++q)
                    f4[q] = ok ? xp[q] : make_float4(0.f, 0.f, 0.f, 0.f);
                const float* ff = (const float*)f4;
#pragma unroll
                for (int j = 0; j < 16; ++j) {
                    float fx = ff[2 * j], fy = ff[2 * j + 1];
                    outu[j] = (uint32)f2bf(fx * sc) | ((uint32)f2bf(fy * sc) << 16);
                }
            }
            uint4* dstA = (uint4*)&As[srow * LDK + half];
#pragma unroll
            for (int q = 0; q < 4; ++q) dstA[q] = ((uint4*)outu)[q];
            const uint4* wp = (const uint4*)((const uint32*)Wt +
                                             srow * 64 + ((k0 + half) >> 1));
            uint4* dstW = (uint4*)&Ws[srow * LDK + half];
#pragma unroll
            for (int q = 0; q < 4; ++q) dstW[q] = wp[q];
        }
        __syncthreads();
#pragma unroll
        for (int ks = 0; ks < 2; ++ks) {
            int koff = ks * 32 + quad * 8;
            short8v a[4], b[4];
#pragma unroll
            for (int t = 0; t < 4; ++t)
                a[t] = *(const short8v*)&As[(wm + t * 16 + l15) * LDK + koff];
#pragma unroll
            for (int u = 0; u < 4; ++u)
                b[u] = *(const short8v*)&Ws[(wn + u * 16 + l15) * LDK + koff];
#pragma unroll
            for (int t = 0; t < 4; ++t)
#pragma unroll
                for (int u = 0; u < 4; ++u)
                    acc[t][u] = __builtin_amdgcn_mfma_f32_16x16x32_bf16(
                        a[t], b[u], acc[t][u], 0, 0, 0);
        }
        __syncthreads();
    }
#pragma unroll
    for (int t = 0; t < 4; ++t) {
#pragma unroll
        for (int r = 0; r < 4; ++r) {
            int grow = row0 + wm + t * 16 + quad * 4 + r;
            if (grow < nrows) {
#pragma unroll
                for (int u = 0; u < 4; ++u)
                    Yb[(size_t)grow * 128 + wn + u * 16 + l15] = f2bf(acc[t][u][r]);
            }
        }
    }
}

// ---- layer-2 projection: Y2b = bf16((ns*relu(bn1(Ab))) @ W2), 128->64 ------
__global__ __launch_bounds__(256) void gemm_mfma2_kernel(
    const uint32* __restrict__ Xb, const ushort16* __restrict__ Wt2,
    const float* __restrict__ ns, const float* __restrict__ stats,
    const float* __restrict__ gamma, const float* __restrict__ beta,
    float invn, ushort16* __restrict__ Y2b, int nrows) {
    constexpr int LDK = 72;
    __shared__ short As[128 * LDK];
    __shared__ short Ws[64 * LDK];
    __shared__ float abl[256];
    int tid = threadIdx.x;
    int row0 = blockIdx.x * 128;
    int wave = tid >> 6, lane = tid & 63;
    int wm = (wave >> 1) * 64, wn = (wave & 1) * 32;
    int l15 = lane & 15, quad = lane >> 4;
    float4v acc[4][2] = {{}};

    if (tid < 128) {
        float mean = stats[tid] * invn;
        float var = stats[128 + tid] * invn - mean * mean;
        float a = rsqrtf(var + 1e-5f) * gamma[tid];
        abl[tid] = a;
        abl[128 + tid] = beta[tid] - mean * a;
    }
    __syncthreads();

#pragma unroll
    for (int p = 0; p < 2; ++p) {
        int k0 = p * 64;
        {
            int srow = tid >> 1;
            int half = (tid & 1) * 32;
            int grow = row0 + srow;
            bool ok = grow < nrows;
            float sc = ok ? ns[grow] : 0.f;
            const uint4* xp = (const uint4*)(Xb + (size_t)grow * 64 + ((k0 + half) >> 1));
            uint4 u4[4];
#pragma unroll
            for (int q = 0; q < 4; ++q)
                u4[q] = ok ? xp[q] : make_uint4(0, 0, 0, 0);
            const uint32* uu = (const uint32*)u4;
            uint32 outu[16];
#pragma unroll
            for (int j = 0; j < 16; ++j) {
                float2 f = bf2f2(uu[j]);
                int c = k0 + half + j * 2;
                f.x = fmaxf(fmaf(f.x, abl[c], abl[128 + c]), 0.f);
                f.y = fmaxf(fmaf(f.y, abl[c + 1], abl[128 + c + 1]), 0.f);
                outu[j] = (uint32)f2bf(f.x * sc) | ((uint32)f2bf(f.y * sc) << 16);
            }
            uint4* dstA = (uint4*)&As[srow * LDK + half];
#pragma unroll
            for (int q = 0; q < 4; ++q) dstA[q] = ((uint4*)outu)[q];
        }
        {
            int srow = tid >> 2;           // 64 rows
            int off = (tid & 3) * 16;      // 16 shorts each
            const uint4* wp = (const uint4*)((const uint32*)Wt2 +
                                             srow * 64 + ((k0 + off) >> 1));
            uint4* dw = (uint4*)&Ws[srow * LDK + off];
            dw[0] = wp[0];
            dw[1] = wp[1];
        }
        __syncthreads();
#pragma unroll
        for (int ks = 0; ks < 2; ++ks) {
            int koff = ks * 32 + quad * 8;
            short8v a[4], b[2];
#pragma unroll
            for (int t = 0; t < 4; ++t)
                a[t] = *(const short8v*)&As[(wm + t * 16 + l15) * LDK + koff];
#pragma unroll
            for (int u = 0; u < 2; ++u)
                b[u] = *(const short8v*)&Ws[(wn + u * 16 + l15) * LDK + koff];
#pragma unroll
            for (int t = 0; t < 4; ++t)
#pragma unroll
                for (int u = 0; u < 2; ++u)
                    acc[t][u] = __builtin_amdgcn_mfma_f32_16x16x32_bf16(
                        a[t], b[u], acc[t][u], 0, 0, 0);
        }
        __syncthreads();
    }
#pragma unroll
    for (int t = 0; t < 4; ++t) {
#pragma unroll
        for (int r = 0; r < 4; ++r) {
            int grow = row0 + wm + t * 16 + quad * 4 + r;
            if (grow < nrows) {
#pragma unroll
                for (int u = 0; u < 2; ++u)
                    Y2b[(size_t)grow * 64 + wn + u * 16 + l15] = f2bf(acc[t][u][r]);
            }
        }
    }
}

// --- CSR aggregation: uint2 gathers, 16-edge batches (8 loads in flight) ----
// lane: par=lane>>5 (edge parity), l32=lane&31 (4 cols via uint2).
__global__ __launch_bounds__(256) void agg128_kernel(
    const uint32* __restrict__ xwb, const int* __restrict__ row_ptr,
    const int* __restrict__ ssrc, const float* __restrict__ nd,
    uint32* __restrict__ outb, int n) {
    int node = blockIdx.x * 4 + (threadIdx.x >> 6);
    if (node >= n) return;
    int lane = threadIdx.x & 63;
    int par = lane >> 5, l32 = lane & 31;
    int beg = row_ptr[node], end = row_ptr[node + 1];
    float x0 = 0.f, x1 = 0.f, x2 = 0.f, x3 = 0.f;
    int e = beg;
    for (; e + 16 <= end; e += 16) {
        int s[8];
#pragma unroll
        for (int j = 0; j < 8; ++j) s[j] = ssrc[e + 2 * j + par];
        uint2 u[8];
#pragma unroll
        for (int j = 0; j < 8; ++j)
            u[j] = *(const uint2*)(xwb + (size_t)s[j] * 64 + l32 * 2);
#pragma unroll
        for (int j = 0; j < 8; ++j) {
            float2 a = bf2f2(u[j].x), b = bf2f2(u[j].y);
            x0 += a.x; x1 += a.y; x2 += b.x; x3 += b.y;
        }
    }
    for (; e + 8 <= end; e += 8) {
        int s[4];
#pragma unroll
        for (int j = 0; j < 4; ++j) s[j] = ssrc[e + 2 * j + par];
        uint2 u[4];
#pragma unroll
        for (int j = 0; j < 4; ++j)
            u[j] = *(const uint2*)(xwb + (size_t)s[j] * 64 + l32 * 2);
#pragma unroll
        for (int j = 0; j < 4; ++j) {
            float2 a = bf2f2(u[j].x), b = bf2f2(u[j].y);
            x0 += a.x; x1 += a.y; x2 += b.x; x3 += b.y;
        }
    }
    for (; e + 2 <= end; e += 2) {
        uint2 u = *(const uint2*)(xwb + (size_t)ssrc[e + par] * 64 + l32 * 2);
        float2 a = bf2f2(u.x), b = bf2f2(u.y);
        x0 += a.x; x1 += a.y; x2 += b.x; x3 += b.y;
    }
    if (e < end && par == 0) {
        uint2 u = *(const uint2*)(xwb + (size_t)ssrc[e] * 64 + l32 * 2);
        float2 a = bf2f2(u.x), b = bf2f2(u.y);
        x0 += a.x; x1 += a.y; x2 += b.x; x3 += b.y;
    }
    x0 += __shfl_down(x0, 32, 64);
    x1 += __shfl_down(x1, 32, 64);
    x2 += __shfl_down(x2, 32, 64);
    x3 += __shfl_down(x3, 32, 64);
    if (par == 0) {
        float s = nd[node];
        uint2 o;
        o.x = (uint32)f2bf(x0 * s) | ((uint32)f2bf(x1 * s) << 16);
        o.y = (uint32)f2bf(x2 * s) | ((uint32)f2bf(x3 * s) << 16);
        *(uint2*)(outb + (size_t)node * 64 + l32 * 2) = o;
    }
}

// ---- layer-2 aggregation: uint2 gathers, 16-edge batches (4 in flight) -----
__global__ __launch_bounds__(256) void agg40_kernel(
    const uint32* __restrict__ y2b, const int* __restrict__ row_ptr,
    const int* __restrict__ ssrc, const float* __restrict__ nd,
    const float* __restrict__ bias, float* __restrict__ out, int n) {
    int node = blockIdx.x * 4 + (threadIdx.x >> 6);
    if (node >= n) return;
    int lane = threadIdx.x & 63;
    int quad = lane >> 4, l16 = lane & 15;
    int beg = row_ptr[node], end = row_ptr[node + 1];
    float x0 = 0.f, x1 = 0.f, x2 = 0.f, x3 = 0.f;
    int e = beg;
    for (; e + 16 <= end; e += 16) {
        int s[4];
#pragma unroll
        for (int j = 0; j < 4; ++j) s[j] = ssrc[e + 4 * j + quad];
        uint2 u[4];
#pragma unroll
        for (int j = 0; j < 4; ++j)
            u[j] = *(const uint2*)(y2b + (size_t)s[j] * 32 + l16 * 2);
#pragma unroll
        for (int j = 0; j < 4; ++j) {
            float2 a = bf2f2(u[j].x), b = bf2f2(u[j].y);
            x0 += a.x; x1 += a.y; x2 += b.x; x3 += b.y;
        }
    }
    for (; e + 4 <= end; e += 4) {
        uint2 u = *(const uint2*)(y2b + (size_t)ssrc[e + quad] * 32 + l16 * 2);
        float2 a = bf2f2(u.x), b = bf2f2(u.y);
        x0 += a.x; x1 += a.y; x2 += b.x; x3 += b.y;
    }
    int r = end - e;
    if (quad < r) {
        uint2 u = *(const uint2*)(y2b + (size_t)ssrc[e + quad] * 32 + l16 * 2);
        float2 a = bf2f2(u.x), b = bf2f2(u.y);
        x0 += a.x; x1 += a.y; x2 += b.x; x3 += b.y;
    }
    x0 += __shfl_down(x0, 32, 64);
    x1 += __shfl_down(x1, 32, 64);
    x2 += __shfl_down(x2, 32, 64);
    x3 += __shfl_down(x3, 32, 64);
    x0 += __shfl_down(x0, 16, 64);
    x1 += __shfl_down(x1, 16, 64);
    x2 += __shfl_down(x2, 16, 64);
    x3 += __shfl_down(x3, 16, 64);
    if (lane < 10) {  // cols 0..39 = lanes 0..9 x 4 cols
        float s = nd[node];
        int c = lane * 4;
        float4 bb = *(const float4*)&bias[c];
        float4 o;
        o.x = fmaf(x0, s, bb.x);
        o.y = fmaf(x1, s, bb.y);
        o.z = fmaf(x2, s, bb.z);
        o.w = fmaf(x3, s, bb.w);
        *(float4*)(out + (size_t)node * 40 + c) = o;
    }
}

// -------- batchnorm stats (bf16 input, uint4 loads, 8 cols/thread) ----------
__global__ __launch_bounds__(256) void bn_reduce_kernel(const uint4* __restrict__ x4,
                                                        float* __restrict__ stats, int n) {
    int tid = threadIdx.x;
    int ctile = tid & 15;    // 16 col-tiles of 8 cols
    int rgrp = tid >> 4;     // 16 row groups
    float s[8] = {}, s2[8] = {};
    for (int r = blockIdx.x * 16 + rgrp; r < n; r += gridDim.x * 16) {
        uint4 u = x4[(size_t)r * 16 + ctile];
        uint32 uu[4] = {u.x, u.y, u.z, u.w};
#pragma unroll
        for (int q = 0; q < 4; ++q) {
            float2 v = bf2f2(uu[q]);
            s[q * 2] += v.x;
            s[q * 2 + 1] += v.y;
            s2[q * 2] = fmaf(v.x, v.x, s2[q * 2]);
            s2[q * 2 + 1] = fmaf(v.y, v.y, s2[q * 2 + 1]);
        }
    }
    __shared__ float ls[128], ls2[128];
    if (tid < 128) { ls[tid] = 0.f; ls2[tid] = 0.f; }
    __syncthreads();
#pragma unroll
    for (int j = 0; j < 8; ++j) {
        atomicAdd(&ls[ctile * 8 + j], s[j]);
        atomicAdd(&ls2[ctile * 8 + j], s2[j]);
    }
    __syncthreads();
    if (tid < 128) {
        atomicAdd(&stats[tid], ls[tid]);
        atomicAdd(&stats[128 + tid], ls2[tid]);
    }
}

// ---------------- launch ----------------

extern "C" void kernel_launch(void* const* d_in, const int* in_sizes, int n_in,
                              void* d_out, int out_size, void* d_ws, size_t ws_size,
                              hipStream_t stream) {
    const float* feat = (const float*)d_in[0];
    const int* edge_src = (const int*)d_in[1];
    const int* edge_dst = (const int*)d_in[2];
    const float* W0 = (const float*)d_in[3];
    const float* W1 = (const float*)d_in[4];
    const float* W2 = (const float*)d_in[5];
    const float* b2 = (const float*)d_in[6];
    const float* g0 = (const float*)d_in[7];
    const float* beta0 = (const float*)d_in[8];
    const float* g1 = (const float*)d_in[9];
    const float* beta1 = (const float*)d_in[10];
    float* out = (float*)d_out;

    const int N = in_sizes[0] / D_H;   // 100000
    const int E = in_sizes[1];         // 1600000
    const int nbuck = (N + 255) >> 8;  // 391
    const float invN = 1.0f / (float)N;

    char* p = (char*)d_ws;
    auto alloc = [&](size_t bytes) {
        char* r = p;
        p += (bytes + 255) & ~(size_t)255;
        return r;
    };
    uint32* Ab = (uint32*)alloc((size_t)N * D_H * 2);   // bf16 A (packed pairs)
    uint32* Bb = (uint32*)alloc((size_t)N * D_H * 2);   // bf16 B / Y2b
    float* ns = (float*)alloc((size_t)N * 4);
    float* nd = (float*)alloc((size_t)N * 4);
    int* row_ptr = (int*)alloc((size_t)(N + 1) * 4);
    int* ssrc = (int*)alloc((size_t)E * 4);
    uint32* packed = (uint32*)alloc((size_t)E * 4);
    uint32* sp = (uint32*)alloc((size_t)E * 4);
    int* M = (int*)alloc((size_t)nbuck * 128 * 4);
    int* Mx = (int*)alloc(((size_t)nbuck * 128 + 4) * 4);
    int* M2 = (int*)alloc((size_t)nbuck * 128 * 4);
    int* Mx2 = (int*)alloc(((size_t)nbuck * 128 + 4) * 4);
    int* bsum = (int*)alloc(256 * 4);
    float* stats0 = (float*)alloc(256 * 4);   // contiguous with stats1
    float* stats1 = (float*)alloc(256 * 4);
    ushort16* Wt0 = (ushort16*)alloc(128 * 128 * 2);
    ushort16* Wt1 = (ushort16*)alloc(128 * 128 * 2);
    ushort16* Wt2 = (ushort16*)alloc(64 * 128 * 2);
    (void)ws_size;

    hipMemsetAsync(stats0, 0, 2048, stream);  // stats0 + stats1 (adjacent)

    const int ggrid = (N + 127) / 128;
    const int agrid = (N + 3) / 4;
    const int nM = nbuck * 128;                            // 50048
    const int sgridM = (nM + SCAN_CHUNK - 1) / SCAN_CHUNK; // 49

    bucket_count2_kernel<<<128, 256, 0, stream>>>(edge_src, edge_dst, M, M2, E, nbuck,
                                                  W0, W1, W2, Wt0, Wt1, Wt2);
    scan1f_kernel<<<2 * sgridM, 256, 0, stream>>>(M, M2, bsum, sgridM, nM);
    scan3f_kernel<<<2 * sgridM, 256, 0, stream>>>(M, M2, bsum, Mx, Mx2, sgridM, nM);
    bucket_scatter2_kernel<<<128, 256, 0, stream>>>(edge_src, edge_dst, Mx, Mx2,
                                                    packed, sp, E, nbuck);
    csr_src_kernel<<<nbuck, 256, 0, stream>>>(packed, Mx, sp, Mx2, row_ptr, nd, ns,
                                              ssrc, E, N, nbuck);

    // layer 0
    gemm_mfma_kernel<false, false><<<ggrid, 256, 0, stream>>>(
        feat, Wt0, ns, nullptr, nullptr, nullptr, invN, (ushort16*)Bb, N);
    agg128_kernel<<<agrid, 256, 0, stream>>>(Bb, row_ptr, ssrc, nd, Ab, N);
    bn_reduce_kernel<<<512, 256, 0, stream>>>((const uint4*)Ab, stats0, N);

    // layer 1
    gemm_mfma_kernel<true, true><<<ggrid, 256, 0, stream>>>(
        Ab, Wt1, ns, stats0, g0, beta0, invN, (ushort16*)Bb, N);
    agg128_kernel<<<agrid, 256, 0, stream>>>(Bb, row_ptr, ssrc, nd, Ab, N);
    bn_reduce_kernel<<<512, 256, 0, stream>>>((const uint4*)Ab, stats1, N);

    // layer 2: project (BN+relu+ns in staging) -> Y2b (N x 64 bf16); agg40 -> out
    gemm_mfma2_kernel<<<ggrid, 256, 0, stream>>>(
        Ab, Wt2, ns, stats1, g1, beta1, invN, (ushort16*)Bb, N);
    agg40_kernel<<<agrid, 256, 0, stream>>>(Bb, row_ptr, ssrc, nd, b2, out, N);
}